// Round 4
// baseline (1093.571 us; speedup 1.0000x reference)
//
#include <hip/hip_runtime.h>
#include <hip/hip_bf16.h>
#include <cstdint>

#define NN 50000
#define NE 800000
#define DH 128
#define TILES 50000    // NE/16
#define NBUCK 4096     // padded bucket count (ei>>4 -> 3125 used)
#define ECHUNK 25      // tiles per wave: 2048 waves * 25 = 51200 >= 50000

typedef __bf16 bf16;
typedef __bf16 bf16x8 __attribute__((ext_vector_type(8)));
typedef float  f32x4  __attribute__((ext_vector_type(4)));

__device__ __forceinline__ float fast_silu(float x) {
    float e = __expf(-x);
    return x * __builtin_amdgcn_rcpf(1.0f + e);
}

// ---------------- k0: weight prep (transpose + bf16) ----------------
__global__ void prep_kernel(const float* __restrict__ W1, const float* __restrict__ W2,
                            const float* __restrict__ W3, const float* __restrict__ b1,
                            const float* __restrict__ g1, const float* __restrict__ bt1,
                            const float* __restrict__ b2, const float* __restrict__ b3,
                            const float* __restrict__ W4,
                            bf16* __restrict__ w1aT, bf16* __restrict__ w1bT,
                            bf16* __restrict__ w2T,  bf16* __restrict__ w3T,
                            float* __restrict__ smalls) {
    int i = blockIdx.x * 256 + threadIdx.x;   // 0..16383
    int n = i >> 7, k = i & 127;
    w1aT[i] = (bf16)W1[k * DH + n];
    w1bT[i] = (bf16)W1[(k + DH) * DH + n];
    w2T[i]  = (bf16)W2[k * DH + n];
    w3T[i]  = (bf16)W3[k * DH + n];
    if (i < DH) {
        smalls[i]          = W1[256 * DH + i]; // w1c
        smalls[DH + i]     = b1[i];
        smalls[2 * DH + i] = g1[i];
        smalls[3 * DH + i] = bt1[i];
        smalls[4 * DH + i] = b2[i];
        smalls[5 * DH + i] = b3[i];
        smalls[6 * DH + i] = W4[i];
    }
}

// ---------------- sort pass 1: zero bucket counters ----------------
__global__ void zero_kernel(int* __restrict__ cnt) {
    cnt[blockIdx.x * 256 + threadIdx.x] = 0;
}

// ---------------- sort pass 2: histogram of ei buckets ----------------
__global__ void hist_kernel(const int* __restrict__ e, int* __restrict__ cnt) {
    int i = blockIdx.x * 256 + threadIdx.x;
    if (i < NE) atomicAdd(&cnt[e[i] >> 4], 1);
}

// ---------------- sort pass 3: exclusive scan (one block) ----------------
__global__ __launch_bounds__(1024) void scan_kernel(const int* __restrict__ cnt,
                                                    int* __restrict__ ofs) {
    __shared__ int buf[1024];
    int t = threadIdx.x;
    int c[4], s0 = 0;
#pragma unroll
    for (int k = 0; k < 4; k++) { c[k] = cnt[t * 4 + k]; s0 += c[k]; }
    buf[t] = s0;
    __syncthreads();
    for (int off = 1; off < 1024; off <<= 1) {
        int v = (t >= off) ? buf[t - off] : 0;
        __syncthreads();
        buf[t] += v;
        __syncthreads();
    }
    int excl = buf[t] - s0;
#pragma unroll
    for (int k = 0; k < 4; k++) { ofs[t * 4 + k] = excl; excl += c[k]; }
}

// ---------------- sort pass 4: scatter-copy edges into sorted order ----------------
__global__ void ssort_kernel(const int* __restrict__ e, const float* __restrict__ d2,
                             const float* __restrict__ dxv, int* __restrict__ ofs,
                             int* __restrict__ sei, int* __restrict__ sej,
                             float* __restrict__ sd2, float* __restrict__ sdx) {
    int i = blockIdx.x * 256 + threadIdx.x;
    if (i >= NE) return;
    int ei = e[i];
    int pos = atomicAdd(&ofs[ei >> 4], 1);
    sei[pos] = ei;
    sej[pos] = e[NE + i];
    sd2[pos] = d2[i];
    sdx[pos * 3 + 0] = dxv[i * 3 + 0];
    sdx[pos * 3 + 1] = dxv[i * 3 + 1];
    sdx[pos * 3 + 2] = dxv[i * 3 + 2];
}

// ---------------- k1: A = h@W1a, B = h@W1b (bf16 out) ----------------
__global__ __launch_bounds__(256) void node_kernel(const float* __restrict__ h,
                                                   const bf16* __restrict__ w1aT,
                                                   const bf16* __restrict__ w1bT,
                                                   bf16* __restrict__ An,
                                                   bf16* __restrict__ Bn) {
    int lane = threadIdx.x & 63, wid = threadIdx.x >> 6;
    int r = lane & 15, g = lane >> 4;
    int wt = blockIdx.x * 4 + wid;
    if (wt >= (NN / 16)) return;
    int base = wt * 16;
    int node = base + r;

    bf16x8 ha[4];
#pragma unroll
    for (int s = 0; s < 4; s++) {
        const float* hp = h + (size_t)node * DH + s * 32 + g * 8;
        float4 p0 = *(const float4*)hp;
        float4 p1 = *(const float4*)(hp + 4);
        ha[s][0] = (bf16)p0.x; ha[s][1] = (bf16)p0.y;
        ha[s][2] = (bf16)p0.z; ha[s][3] = (bf16)p0.w;
        ha[s][4] = (bf16)p1.x; ha[s][5] = (bf16)p1.y;
        ha[s][6] = (bf16)p1.z; ha[s][7] = (bf16)p1.w;
    }
#pragma unroll
    for (int t = 0; t < 16; t++) {
        const bf16* wmat = (t < 8) ? w1aT : w1bT;
        int n = (t & 7) * 16 + r;
        f32x4 acc = {0.f, 0.f, 0.f, 0.f};
#pragma unroll
        for (int s = 0; s < 4; s++) {
            bf16x8 wb = *(const bf16x8*)(wmat + n * DH + s * 32 + g * 8);
            acc = __builtin_amdgcn_mfma_f32_16x16x32_bf16(ha[s], wb, acc, 0, 0, 0);
        }
        bf16* dst = (t < 8) ? An : Bn;
#pragma unroll
        for (int jj = 0; jj < 4; jj++)
            dst[(size_t)(base + g * 4 + jj) * DH + (t & 7) * 16 + r] = (bf16)acc[jj];
    }
}

// ---------------- k2: out = x ----------------
__global__ void init_kernel(const float* __restrict__ x, float* __restrict__ out, int n) {
    int i = blockIdx.x * 256 + threadIdx.x;
    if (i < n) out[i] = x[i];
}

// ---------------- k3: fused edge MLP + scatter (sorted edges) ----------------
// LDS 108032 B -> 1 block/CU, 8 waves. Grid 256 blocks, XCD-chunked waves:
// each wave owns ECHUNK consecutive sorted tiles -> An gathers + out atomics
// are XCD-local (~1.6 MB An slice per XCD). Bn stays random.
__global__ __launch_bounds__(512, 2) void edge_kernel(
    const bf16* __restrict__ An, const bf16* __restrict__ Bn,
    const bf16* __restrict__ w2T, const bf16* __restrict__ w3T,
    const float* __restrict__ smalls, const float* __restrict__ b4p,
    const int* __restrict__ sei, const int* __restrict__ sej,
    const float* __restrict__ sd2, const float* __restrict__ sdx,
    float* __restrict__ out) {
    __shared__ __align__(16) bf16 sW2[128 * 136];
    __shared__ __align__(16) bf16 sW3[128 * 136];
    __shared__ __align__(16) bf16 sY[8 * 16 * 136];
    __shared__ float sSm[7 * 128];

    int tid = threadIdx.x;
    for (int c = tid; c < 2048; c += 512) {
        int row = c >> 4, col = (c & 15) * 8;
        *(bf16x8*)&sW2[row * 136 + col] = *(const bf16x8*)&w2T[row * 128 + col];
        *(bf16x8*)&sW3[row * 136 + col] = *(const bf16x8*)&w3T[row * 128 + col];
    }
    if (tid < 128) {
#pragma unroll
        for (int a = 0; a < 7; a++) sSm[a * 128 + tid] = smalls[a * 128 + tid];
    }
    __syncthreads();

    const float* s_w1c = sSm;
    const float* s_b1  = sSm + 128;
    const float* s_g1  = sSm + 256;
    const float* s_bt1 = sSm + 384;
    const float* s_b2  = sSm + 512;
    const float* s_b3  = sSm + 640;
    const float* s_W4  = sSm + 768;
    float b4v = b4p[0];

    int lane = tid & 63, wid = tid >> 6;
    int r = lane & 15, g = lane >> 4;
    bf16* yw = &sY[wid * 16 * 136];

    // XCD-chunked wave -> contiguous sorted-tile range
    int bid = blockIdx.x;                 // 0..255
    int swz = (bid & 7) * 32 + (bid >> 3);
    int wave_g = swz * 8 + wid;           // 0..2047
    int tile = wave_g * ECHUNK;
    int tend = tile + ECHUNK;
    if (tend > TILES) tend = TILES;

    bf16x8 av[4], bv[4];
    int ei_r = 0, ej_r = 0; float d2_r = 0.f;
    if (tile < tend) {                    // prologue: tile-0 indices + data
        ei_r = sei[tile * 16 + r];
        ej_r = sej[tile * 16 + r];
        d2_r = sd2[tile * 16 + r];
        const bf16* Ar = An + (size_t)ei_r * DH;
        const bf16* Br = Bn + (size_t)ej_r * DH;
#pragma unroll
        for (int s = 0; s < 4; s++) {
            av[s] = *(const bf16x8*)(Ar + s * 32 + g * 8);
            bv[s] = *(const bf16x8*)(Br + s * 32 + g * 8);
        }
    }

    for (; tile < tend; ++tile) {
        int base = tile * 16;
        int nt = tile + 1;
        bool has_n = (nt < tend);
        int ei_n = 0, ej_n = 0; float d2_n = 0.f;
        if (has_n) {                      // next tile's indices (coalesced)
            ei_n = sei[nt * 16 + r];
            ej_n = sej[nt * 16 + r];
            d2_n = sd2[nt * 16 + r];
        }
        // scatter operand for current tile, loaded early
        int m = lane >> 2, c3 = lane & 3;
        float dxm = (c3 < 3) ? sdx[(size_t)(base + m) * 3 + c3] : 0.f;

        // z = silu(A[ei] + B[ej] + d2*w1c + b1), A-frag layout
        float z[4][8];
        float d2v = d2_r;
#pragma unroll
        for (int s = 0; s < 4; s++) {
#pragma unroll
            for (int j = 0; j < 8; j++) {
                int f = s * 32 + g * 8 + j;
                float zz = (float)av[s][j] + (float)bv[s][j] + d2v * s_w1c[f] + s_b1[f];
                z[s][j] = fast_silu(zz);
            }
        }
        int ei_cur = ei_r;                 // keep for scatter

        // issue NEXT tile's gathers now; they complete under GEMM1+GEMM2
        if (has_n) {
            const bf16* Arn = An + (size_t)ei_n * DH;
            const bf16* Brn = Bn + (size_t)ej_n * DH;
#pragma unroll
            for (int s = 0; s < 4; s++) {
                av[s] = *(const bf16x8*)(Arn + s * 32 + g * 8);
                bv[s] = *(const bf16x8*)(Brn + s * 32 + g * 8);
            }
            ei_r = ei_n; ej_r = ej_n; d2_r = d2_n;
        }

        // LayerNorm across 128 features (4 lanes per row: xor 16, 32)
        float sum = 0.f, sq = 0.f;
#pragma unroll
        for (int s = 0; s < 4; s++)
#pragma unroll
            for (int j = 0; j < 8; j++) { sum += z[s][j]; sq += z[s][j] * z[s][j]; }
        sum += __shfl_xor(sum, 16); sq += __shfl_xor(sq, 16);
        sum += __shfl_xor(sum, 32); sq += __shfl_xor(sq, 32);
        float mu = sum * 0.0078125f;
        float var = sq * 0.0078125f - mu * mu;
        float rs = __builtin_amdgcn_rsqf(var + 1e-5f);

        bf16x8 af[4];
#pragma unroll
        for (int s = 0; s < 4; s++)
#pragma unroll
            for (int j = 0; j < 8; j++) {
                int f = s * 32 + g * 8 + j;
                af[s][j] = (bf16)((z[s][j] - mu) * rs * s_g1[f] + s_bt1[f]);
            }

        // GEMM1: y = silu(zn @ W2 + b2) -> per-wave LDS tile (layout exchange)
#pragma unroll
        for (int t = 0; t < 8; t++) {
            f32x4 acc = {0.f, 0.f, 0.f, 0.f};
#pragma unroll
            for (int s = 0; s < 4; s++) {
                bf16x8 wb = *(const bf16x8*)&sW2[(t * 16 + r) * 136 + s * 32 + g * 8];
                acc = __builtin_amdgcn_mfma_f32_16x16x32_bf16(af[s], wb, acc, 0, 0, 0);
            }
            int n = t * 16 + r;
            float b2n = s_b2[n];
#pragma unroll
            for (int jj = 0; jj < 4; jj++)
                yw[(g * 4 + jj) * 136 + n] = (bf16)fast_silu(acc[jj] + b2n);
        }
        bf16x8 a2[4];
#pragma unroll
        for (int s = 0; s < 4; s++)
            a2[s] = *(const bf16x8*)&yw[r * 136 + s * 32 + g * 8];

        // GEMM2 + fused silu*W4 reduction
        float part[4] = {0.f, 0.f, 0.f, 0.f};
#pragma unroll
        for (int t = 0; t < 8; t++) {
            f32x4 acc = {0.f, 0.f, 0.f, 0.f};
#pragma unroll
            for (int s = 0; s < 4; s++) {
                bf16x8 wb = *(const bf16x8*)&sW3[(t * 16 + r) * 136 + s * 32 + g * 8];
                acc = __builtin_amdgcn_mfma_f32_16x16x32_bf16(a2[s], wb, acc, 0, 0, 0);
            }
            int n = t * 16 + r;
            float b3n = s_b3[n], w4n = s_W4[n];
#pragma unroll
            for (int jj = 0; jj < 4; jj++)
                part[jj] += fast_silu(acc[jj] + b3n) * w4n;
        }
#pragma unroll
        for (int jj = 0; jj < 4; jj++) {
            part[jj] += __shfl_xor(part[jj], 1);
            part[jj] += __shfl_xor(part[jj], 2);
            part[jj] += __shfl_xor(part[jj], 4);
            part[jj] += __shfl_xor(part[jj], 8);
        }
        // scatter: lane = m*4 + c
        {
            int jj = m & 3;
            float sc = (jj == 0) ? part[0] : (jj == 1) ? part[1]
                     : (jj == 2) ? part[2] : part[3];
            float scale = sc + b4v;
            int eim = __shfl(ei_cur, m);
            if (c3 < 3)
                atomicAdd(&out[(size_t)eim * 3 + c3], dxm * scale);
        }
    }
}

extern "C" void kernel_launch(void* const* d_in, const int* in_sizes, int n_in,
                              void* d_out, int out_size, void* d_ws, size_t ws_size,
                              hipStream_t stream) {
    const float* h   = (const float*)d_in[0];
    const float* x   = (const float*)d_in[1];
    const int*   e   = (const int*)d_in[2];
    const float* dxv = (const float*)d_in[3];
    const float* d2  = (const float*)d_in[4];
    const float* W1  = (const float*)d_in[5];
    const float* b1  = (const float*)d_in[6];
    const float* g1  = (const float*)d_in[7];
    const float* bt1 = (const float*)d_in[8];
    const float* W2  = (const float*)d_in[9];
    const float* b2  = (const float*)d_in[10];
    const float* W3  = (const float*)d_in[11];
    const float* b3  = (const float*)d_in[12];
    const float* W4  = (const float*)d_in[13];
    const float* b4  = (const float*)d_in[14];

    char* ws = (char*)d_ws;
    bf16* An     = (bf16*)(ws);                       // 12,800,000
    bf16* Bn     = (bf16*)(ws + 12800000);            // 12,800,000
    bf16* w1aT   = (bf16*)(ws + 25600000);
    bf16* w1bT   = (bf16*)(ws + 25600000 + 32768);
    bf16* w2T    = (bf16*)(ws + 25600000 + 65536);
    bf16* w3T    = (bf16*)(ws + 25600000 + 98304);
    float* smalls = (float*)(ws + 25600000 + 131072); // 3584
    int*   cnt   = (int*)(ws + 25734656);             // 16384
    int*   ofs   = (int*)(ws + 25751040);             // 16384
    int*   sei   = (int*)(ws + 25767424);             // 3,200,000
    int*   sej   = (int*)(ws + 28967424);             // 3,200,000
    float* sd2   = (float*)(ws + 32167424);           // 3,200,000
    float* sdx   = (float*)(ws + 35367424);           // 9,600,000
    float* out   = (float*)d_out;

    zero_kernel<<<16, 256, 0, stream>>>(cnt);
    prep_kernel<<<64, 256, 0, stream>>>(W1, W2, W3, b1, g1, bt1, b2, b3, W4,
                                        w1aT, w1bT, w2T, w3T, smalls);
    hist_kernel<<<(NE + 255) / 256, 256, 0, stream>>>(e, cnt);
    scan_kernel<<<1, 1024, 0, stream>>>(cnt, ofs);
    ssort_kernel<<<(NE + 255) / 256, 256, 0, stream>>>(e, d2, dxv, ofs,
                                                       sei, sej, sd2, sdx);
    node_kernel<<<(NN / 16 + 3) / 4, 256, 0, stream>>>(h, w1aT, w1bT, An, Bn);
    init_kernel<<<(NN * 3 + 255) / 256, 256, 0, stream>>>(x, out, NN * 3);
    edge_kernel<<<256, 512, 0, stream>>>(An, Bn, w2T, w3T, smalls, b4,
                                         sei, sej, sd2, sdx, out);
}

// Round 5
// 779.990 us; speedup vs baseline: 1.4020x; 1.4020x over previous
//
#include <hip/hip_runtime.h>
#include <hip/hip_bf16.h>
#include <cstdint>

#define NN 50000
#define NE 800000
#define DH 128
#define TILES 50000    // NE/16
#define NBUCK 4096     // padded bucket count (ei>>4 -> 3125 used)
#define ECHUNK 25      // tiles per wave: 2048 waves * 25 = 51200 >= 50000

typedef __bf16 bf16;
typedef __bf16 bf16x8 __attribute__((ext_vector_type(8)));
typedef float  f32x4  __attribute__((ext_vector_type(4)));

__device__ __forceinline__ float fast_silu(float x) {
    float e = __expf(-x);
    return x * __builtin_amdgcn_rcpf(1.0f + e);
}

// ---------------- k0: weight prep (transpose + bf16) ----------------
__global__ void prep_kernel(const float* __restrict__ W1, const float* __restrict__ W2,
                            const float* __restrict__ W3, const float* __restrict__ b1,
                            const float* __restrict__ g1, const float* __restrict__ bt1,
                            const float* __restrict__ b2, const float* __restrict__ b3,
                            const float* __restrict__ W4,
                            bf16* __restrict__ w1aT, bf16* __restrict__ w1bT,
                            bf16* __restrict__ w2T,  bf16* __restrict__ w3T,
                            float* __restrict__ smalls) {
    int i = blockIdx.x * 256 + threadIdx.x;   // 0..16383
    int n = i >> 7, k = i & 127;
    w1aT[i] = (bf16)W1[k * DH + n];
    w1bT[i] = (bf16)W1[(k + DH) * DH + n];
    w2T[i]  = (bf16)W2[k * DH + n];
    w3T[i]  = (bf16)W3[k * DH + n];
    if (i < DH) {
        smalls[i]          = W1[256 * DH + i]; // w1c
        smalls[DH + i]     = b1[i];
        smalls[2 * DH + i] = g1[i];
        smalls[3 * DH + i] = bt1[i];
        smalls[4 * DH + i] = b2[i];
        smalls[5 * DH + i] = b3[i];
        smalls[6 * DH + i] = W4[i];
    }
}

// ---------------- sort pass 1: zero bucket counters ----------------
__global__ void zero_kernel(int* __restrict__ cnt) {
    cnt[blockIdx.x * 256 + threadIdx.x] = 0;
}

// ---------------- sort pass 2: histogram of ei buckets ----------------
__global__ void hist_kernel(const int* __restrict__ e, int* __restrict__ cnt) {
    int i = blockIdx.x * 256 + threadIdx.x;
    if (i < NE) atomicAdd(&cnt[e[i] >> 4], 1);
}

// ---------------- sort pass 3: exclusive scan (one block) ----------------
__global__ __launch_bounds__(1024) void scan_kernel(const int* __restrict__ cnt,
                                                    int* __restrict__ ofs) {
    __shared__ int buf[1024];
    int t = threadIdx.x;
    int c[4], s0 = 0;
#pragma unroll
    for (int k = 0; k < 4; k++) { c[k] = cnt[t * 4 + k]; s0 += c[k]; }
    buf[t] = s0;
    __syncthreads();
    for (int off = 1; off < 1024; off <<= 1) {
        int v = (t >= off) ? buf[t - off] : 0;
        __syncthreads();
        buf[t] += v;
        __syncthreads();
    }
    int excl = buf[t] - s0;
#pragma unroll
    for (int k = 0; k < 4; k++) { ofs[t * 4 + k] = excl; excl += c[k]; }
}

// ---------------- sort pass 4: scatter-copy edges into sorted order ----------------
__global__ void ssort_kernel(const int* __restrict__ e, const float* __restrict__ d2,
                             const float* __restrict__ dxv, int* __restrict__ ofs,
                             int* __restrict__ sei, int* __restrict__ sej,
                             float* __restrict__ sd2, float* __restrict__ sdx) {
    int i = blockIdx.x * 256 + threadIdx.x;
    if (i >= NE) return;
    int ei = e[i];
    int pos = atomicAdd(&ofs[ei >> 4], 1);
    sei[pos] = ei;
    sej[pos] = e[NE + i];
    sd2[pos] = d2[i];
    sdx[pos * 3 + 0] = dxv[i * 3 + 0];
    sdx[pos * 3 + 1] = dxv[i * 3 + 1];
    sdx[pos * 3 + 2] = dxv[i * 3 + 2];
}

// ---------------- k1: A = h@W1a, B = h@W1b (bf16 out) ----------------
__global__ __launch_bounds__(256) void node_kernel(const float* __restrict__ h,
                                                   const bf16* __restrict__ w1aT,
                                                   const bf16* __restrict__ w1bT,
                                                   bf16* __restrict__ An,
                                                   bf16* __restrict__ Bn) {
    int lane = threadIdx.x & 63, wid = threadIdx.x >> 6;
    int r = lane & 15, g = lane >> 4;
    int wt = blockIdx.x * 4 + wid;
    if (wt >= (NN / 16)) return;
    int base = wt * 16;
    int node = base + r;

    bf16x8 ha[4];
#pragma unroll
    for (int s = 0; s < 4; s++) {
        const float* hp = h + (size_t)node * DH + s * 32 + g * 8;
        float4 p0 = *(const float4*)hp;
        float4 p1 = *(const float4*)(hp + 4);
        ha[s][0] = (bf16)p0.x; ha[s][1] = (bf16)p0.y;
        ha[s][2] = (bf16)p0.z; ha[s][3] = (bf16)p0.w;
        ha[s][4] = (bf16)p1.x; ha[s][5] = (bf16)p1.y;
        ha[s][6] = (bf16)p1.z; ha[s][7] = (bf16)p1.w;
    }
#pragma unroll
    for (int t = 0; t < 16; t++) {
        const bf16* wmat = (t < 8) ? w1aT : w1bT;
        int n = (t & 7) * 16 + r;
        f32x4 acc = {0.f, 0.f, 0.f, 0.f};
#pragma unroll
        for (int s = 0; s < 4; s++) {
            bf16x8 wb = *(const bf16x8*)(wmat + n * DH + s * 32 + g * 8);
            acc = __builtin_amdgcn_mfma_f32_16x16x32_bf16(ha[s], wb, acc, 0, 0, 0);
        }
        bf16* dst = (t < 8) ? An : Bn;
#pragma unroll
        for (int jj = 0; jj < 4; jj++)
            dst[(size_t)(base + g * 4 + jj) * DH + (t & 7) * 16 + r] = (bf16)acc[jj];
    }
}

// ---------------- k2: out = x ----------------
__global__ void init_kernel(const float* __restrict__ x, float* __restrict__ out, int n) {
    int i = blockIdx.x * 256 + threadIdx.x;
    if (i < n) out[i] = x[i];
}

// ---------------- k3: fused edge MLP + scatter (sorted edges) ----------------
// R1-proven no-spill body (inline gathers, NO register prefetch -- R3/R4's
// prefetch pushed past the 128-VGPR cliff and spill-amplified FETCH by ~1GB).
// Sorted inputs: An gathers hit 4KB bucket slices (L1-resident), atomics
// node-local, index/d2/dx streams coalesced. LDS 108KB -> 1 block/CU.
__global__ __launch_bounds__(512, 2) void edge_kernel(
    const bf16* __restrict__ An, const bf16* __restrict__ Bn,
    const bf16* __restrict__ w2T, const bf16* __restrict__ w3T,
    const float* __restrict__ smalls, const float* __restrict__ b4p,
    const int* __restrict__ sei, const int* __restrict__ sej,
    const float* __restrict__ sd2, const float* __restrict__ sdx,
    float* __restrict__ out) {
    __shared__ __align__(16) bf16 sW2[128 * 136];
    __shared__ __align__(16) bf16 sW3[128 * 136];
    __shared__ __align__(16) bf16 sY[8 * 16 * 136];
    __shared__ float sSm[7 * 128];

    int tid = threadIdx.x;
    for (int c = tid; c < 2048; c += 512) {
        int row = c >> 4, col = (c & 15) * 8;
        *(bf16x8*)&sW2[row * 136 + col] = *(const bf16x8*)&w2T[row * 128 + col];
        *(bf16x8*)&sW3[row * 136 + col] = *(const bf16x8*)&w3T[row * 128 + col];
    }
    if (tid < 128) {
#pragma unroll
        for (int a = 0; a < 7; a++) sSm[a * 128 + tid] = smalls[a * 128 + tid];
    }
    __syncthreads();

    const float* s_w1c = sSm;
    const float* s_b1  = sSm + 128;
    const float* s_g1  = sSm + 256;
    const float* s_bt1 = sSm + 384;
    const float* s_b2  = sSm + 512;
    const float* s_b3  = sSm + 640;
    const float* s_W4  = sSm + 768;
    float b4v = b4p[0];

    int lane = tid & 63, wid = tid >> 6;
    int r = lane & 15, g = lane >> 4;
    bf16* yw = &sY[wid * 16 * 136];

    // XCD-chunked wave -> contiguous sorted-tile range
    int bid = blockIdx.x;                 // 0..255
    int swz = (bid & 7) * 32 + (bid >> 3);
    int wave_g = swz * 8 + wid;           // 0..2047
    int tile = wave_g * ECHUNK;
    int tend = tile + ECHUNK;
    if (tend > TILES) tend = TILES;

    for (; tile < tend; ++tile) {
        int base = tile * 16;
        int ei = sei[base + r];
        int ej = sej[base + r];
        float d2v = sd2[base + r];
        const bf16* Ar = An + (size_t)ei * DH;
        const bf16* Br = Bn + (size_t)ej * DH;

        // z = silu(A[ei] + B[ej] + d2*w1c + b1), in A-frag layout
        float z[4][8];
#pragma unroll
        for (int s = 0; s < 4; s++) {
            bf16x8 av = *(const bf16x8*)(Ar + s * 32 + g * 8);
            bf16x8 bv = *(const bf16x8*)(Br + s * 32 + g * 8);
#pragma unroll
            for (int j = 0; j < 8; j++) {
                int f = s * 32 + g * 8 + j;
                float zz = (float)av[j] + (float)bv[j] + d2v * s_w1c[f] + s_b1[f];
                z[s][j] = fast_silu(zz);
            }
        }
        // LayerNorm across 128 features (4 lanes per row: xor 16, 32)
        float sum = 0.f, sq = 0.f;
#pragma unroll
        for (int s = 0; s < 4; s++)
#pragma unroll
            for (int j = 0; j < 8; j++) { sum += z[s][j]; sq += z[s][j] * z[s][j]; }
        sum += __shfl_xor(sum, 16); sq += __shfl_xor(sq, 16);
        sum += __shfl_xor(sum, 32); sq += __shfl_xor(sq, 32);
        float mu = sum * 0.0078125f;
        float var = sq * 0.0078125f - mu * mu;
        float rs = __builtin_amdgcn_rsqf(var + 1e-5f);

        bf16x8 af[4];
#pragma unroll
        for (int s = 0; s < 4; s++)
#pragma unroll
            for (int j = 0; j < 8; j++) {
                int f = s * 32 + g * 8 + j;
                af[s][j] = (bf16)((z[s][j] - mu) * rs * s_g1[f] + s_bt1[f]);
            }

        // GEMM1: y = silu(zn @ W2 + b2) -> per-wave LDS tile (layout exchange)
#pragma unroll
        for (int t = 0; t < 8; t++) {
            f32x4 acc = {0.f, 0.f, 0.f, 0.f};
#pragma unroll
            for (int s = 0; s < 4; s++) {
                bf16x8 wb = *(const bf16x8*)&sW2[(t * 16 + r) * 136 + s * 32 + g * 8];
                acc = __builtin_amdgcn_mfma_f32_16x16x32_bf16(af[s], wb, acc, 0, 0, 0);
            }
            int n = t * 16 + r;
            float b2n = s_b2[n];
#pragma unroll
            for (int jj = 0; jj < 4; jj++)
                yw[(g * 4 + jj) * 136 + n] = (bf16)fast_silu(acc[jj] + b2n);
        }
        // reload y as A-fragments
        bf16x8 a2[4];
#pragma unroll
        for (int s = 0; s < 4; s++)
            a2[s] = *(const bf16x8*)&yw[r * 136 + s * 32 + g * 8];

        // GEMM2 + fused silu*W4 reduction
        float part[4] = {0.f, 0.f, 0.f, 0.f};
#pragma unroll
        for (int t = 0; t < 8; t++) {
            f32x4 acc = {0.f, 0.f, 0.f, 0.f};
#pragma unroll
            for (int s = 0; s < 4; s++) {
                bf16x8 wb = *(const bf16x8*)&sW3[(t * 16 + r) * 136 + s * 32 + g * 8];
                acc = __builtin_amdgcn_mfma_f32_16x16x32_bf16(a2[s], wb, acc, 0, 0, 0);
            }
            int n = t * 16 + r;
            float b3n = s_b3[n], w4n = s_W4[n];
#pragma unroll
            for (int jj = 0; jj < 4; jj++)
                part[jj] += fast_silu(acc[jj] + b3n) * w4n;
        }
#pragma unroll
        for (int jj = 0; jj < 4; jj++) {
            part[jj] += __shfl_xor(part[jj], 1);
            part[jj] += __shfl_xor(part[jj], 2);
            part[jj] += __shfl_xor(part[jj], 4);
            part[jj] += __shfl_xor(part[jj], 8);
        }
        // scatter: lane = m*4 + c  (edge m = lane>>2, component c = lane&3)
        {
            int m = lane >> 2, c3 = lane & 3;
            int jj = m & 3;
            float sc = (jj == 0) ? part[0] : (jj == 1) ? part[1]
                     : (jj == 2) ? part[2] : part[3];
            float scale = sc + b4v;
            int eim = __shfl(ei, m);
            if (c3 < 3)
                atomicAdd(&out[(size_t)eim * 3 + c3],
                          sdx[(size_t)(base + m) * 3 + c3] * scale);
        }
    }
}

extern "C" void kernel_launch(void* const* d_in, const int* in_sizes, int n_in,
                              void* d_out, int out_size, void* d_ws, size_t ws_size,
                              hipStream_t stream) {
    const float* h   = (const float*)d_in[0];
    const float* x   = (const float*)d_in[1];
    const int*   e   = (const int*)d_in[2];
    const float* dxv = (const float*)d_in[3];
    const float* d2  = (const float*)d_in[4];
    const float* W1  = (const float*)d_in[5];
    const float* b1  = (const float*)d_in[6];
    const float* g1  = (const float*)d_in[7];
    const float* bt1 = (const float*)d_in[8];
    const float* W2  = (const float*)d_in[9];
    const float* b2  = (const float*)d_in[10];
    const float* W3  = (const float*)d_in[11];
    const float* b3  = (const float*)d_in[12];
    const float* W4  = (const float*)d_in[13];
    const float* b4  = (const float*)d_in[14];

    char* ws = (char*)d_ws;
    bf16* An     = (bf16*)(ws);                       // 12,800,000
    bf16* Bn     = (bf16*)(ws + 12800000);            // 12,800,000
    bf16* w1aT   = (bf16*)(ws + 25600000);
    bf16* w1bT   = (bf16*)(ws + 25600000 + 32768);
    bf16* w2T    = (bf16*)(ws + 25600000 + 65536);
    bf16* w3T    = (bf16*)(ws + 25600000 + 98304);
    float* smalls = (float*)(ws + 25600000 + 131072); // 3584
    int*   cnt   = (int*)(ws + 25734656);             // 16384
    int*   ofs   = (int*)(ws + 25751040);             // 16384
    int*   sei   = (int*)(ws + 25767424);             // 3,200,000
    int*   sej   = (int*)(ws + 28967424);             // 3,200,000
    float* sd2   = (float*)(ws + 32167424);           // 3,200,000
    float* sdx   = (float*)(ws + 35367424);           // 9,600,000
    float* out   = (float*)d_out;

    zero_kernel<<<16, 256, 0, stream>>>(cnt);
    prep_kernel<<<64, 256, 0, stream>>>(W1, W2, W3, b1, g1, bt1, b2, b3, W4,
                                        w1aT, w1bT, w2T, w3T, smalls);
    hist_kernel<<<(NE + 255) / 256, 256, 0, stream>>>(e, cnt);
    scan_kernel<<<1, 1024, 0, stream>>>(cnt, ofs);
    ssort_kernel<<<(NE + 255) / 256, 256, 0, stream>>>(e, d2, dxv, ofs,
                                                       sei, sej, sd2, sdx);
    node_kernel<<<(NN / 16 + 3) / 4, 256, 0, stream>>>(h, w1aT, w1bT, An, Bn);
    init_kernel<<<(NN * 3 + 255) / 256, 256, 0, stream>>>(x, out, NN * 3);
    edge_kernel<<<256, 512, 0, stream>>>(An, Bn, w2T, w3T, smalls, b4,
                                         sei, sej, sd2, sdx, out);
}

// Round 6
// 423.142 us; speedup vs baseline: 2.5844x; 1.8433x over previous
//
#include <hip/hip_runtime.h>
#include <hip/hip_bf16.h>
#include <cstdint>

#define NN 50000
#define NE 800000
#define DH 128
#define TILES 50000
#define NCHUNK 4
#define CT (TILES / NCHUNK)   // 12500 tiles per chunk

typedef __bf16 bf16;
typedef __bf16 bf16x8 __attribute__((ext_vector_type(8)));
typedef float  f32x4  __attribute__((ext_vector_type(4)));

__device__ __forceinline__ float fast_silu(float x) {
    float e = __expf(-x);
    return x * __builtin_amdgcn_rcpf(1.0f + e);
}

// ---------------- k0: weight prep (transpose + bf16) ----------------
__global__ void prep_kernel(const float* __restrict__ W1, const float* __restrict__ W2,
                            const float* __restrict__ W3, const float* __restrict__ b1,
                            const float* __restrict__ g1, const float* __restrict__ bt1,
                            const float* __restrict__ b2, const float* __restrict__ b3,
                            const float* __restrict__ W4,
                            bf16* __restrict__ w1aT, bf16* __restrict__ w1bT,
                            bf16* __restrict__ w2T,  bf16* __restrict__ w3T,
                            float* __restrict__ smalls) {
    int i = blockIdx.x * 256 + threadIdx.x;   // 0..16383
    int n = i >> 7, k = i & 127;
    w1aT[i] = (bf16)W1[k * DH + n];
    w1bT[i] = (bf16)W1[(k + DH) * DH + n];
    w2T[i]  = (bf16)W2[k * DH + n];
    w3T[i]  = (bf16)W3[k * DH + n];
    if (i < DH) {
        smalls[i]          = W1[256 * DH + i]; // w1c
        smalls[DH + i]     = b1[i];
        smalls[2 * DH + i] = g1[i];
        smalls[3 * DH + i] = bt1[i];
        smalls[4 * DH + i] = b2[i];
        smalls[5 * DH + i] = b3[i];
        smalls[6 * DH + i] = W4[i];
    }
}

// ---------------- k1: A = h@W1a, B = h@W1b (bf16 out) ----------------
__global__ __launch_bounds__(256) void node_kernel(const float* __restrict__ h,
                                                   const bf16* __restrict__ w1aT,
                                                   const bf16* __restrict__ w1bT,
                                                   bf16* __restrict__ An,
                                                   bf16* __restrict__ Bn) {
    int lane = threadIdx.x & 63, wid = threadIdx.x >> 6;
    int r = lane & 15, g = lane >> 4;
    int wt = blockIdx.x * 4 + wid;
    if (wt >= (NN / 16)) return;
    int base = wt * 16;
    int node = base + r;

    bf16x8 ha[4];
#pragma unroll
    for (int s = 0; s < 4; s++) {
        const float* hp = h + (size_t)node * DH + s * 32 + g * 8;
        float4 p0 = *(const float4*)hp;
        float4 p1 = *(const float4*)(hp + 4);
        ha[s][0] = (bf16)p0.x; ha[s][1] = (bf16)p0.y;
        ha[s][2] = (bf16)p0.z; ha[s][3] = (bf16)p0.w;
        ha[s][4] = (bf16)p1.x; ha[s][5] = (bf16)p1.y;
        ha[s][6] = (bf16)p1.z; ha[s][7] = (bf16)p1.w;
    }
#pragma unroll
    for (int t = 0; t < 16; t++) {
        const bf16* wmat = (t < 8) ? w1aT : w1bT;
        int n = (t & 7) * 16 + r;
        f32x4 acc = {0.f, 0.f, 0.f, 0.f};
#pragma unroll
        for (int s = 0; s < 4; s++) {
            bf16x8 wb = *(const bf16x8*)(wmat + n * DH + s * 32 + g * 8);
            acc = __builtin_amdgcn_mfma_f32_16x16x32_bf16(ha[s], wb, acc, 0, 0, 0);
        }
        bf16* dst = (t < 8) ? An : Bn;
#pragma unroll
        for (int jj = 0; jj < 4; jj++)
            dst[(size_t)(base + g * 4 + jj) * DH + (t & 7) * 16 + r] = (bf16)acc[jj];
    }
}

// ---------------- k2: out = x ----------------
__global__ void init_kernel(const float* __restrict__ x, float* __restrict__ out, int n) {
    int i = blockIdx.x * 256 + threadIdx.x;
    if (i < n) out[i] = x[i];
}

// ---------------- Phase A: gather + silu + LN -> Z (A-frag layout) ----------------
// No weight LDS, no MFMA: tiny LDS + modest VGPR -> high occupancy hides
// the random An/Bn gather latency. Z written in MFMA A-fragment order so
// each wave's 4 stores (and Phase B's 4 loads) are contiguous 1KB.
__global__ __launch_bounds__(256) void edgeA_kernel(
    const bf16* __restrict__ An, const bf16* __restrict__ Bn,
    const float* __restrict__ smalls, const int* __restrict__ e,
    const float* __restrict__ d2, bf16* __restrict__ Z, int tile0) {
    __shared__ float sSm[4 * 128];
    int tid = threadIdx.x;
    if (tid < 128) {
#pragma unroll
        for (int a = 0; a < 4; a++) sSm[a * 128 + tid] = smalls[a * 128 + tid];
    }
    __syncthreads();
    const float* s_w1c = sSm;
    const float* s_b1  = sSm + 128;
    const float* s_g1  = sSm + 256;
    const float* s_bt1 = sSm + 384;

    int lane = tid & 63, wid = tid >> 6;
    int r = lane & 15, g = lane >> 4;
    int wgid = blockIdx.x * 4 + wid;
    int nw = gridDim.x * 4;

    for (int lt = wgid; lt < CT; lt += nw) {
        int base = (tile0 + lt) * 16;
        int ei = e[base + r];
        int ej = e[NE + base + r];
        float d2v = d2[base + r];
        const bf16* Ar = An + (size_t)ei * DH;
        const bf16* Br = Bn + (size_t)ej * DH;

        float z[4][8];
#pragma unroll
        for (int s = 0; s < 4; s++) {
            bf16x8 av = *(const bf16x8*)(Ar + s * 32 + g * 8);
            bf16x8 bv = *(const bf16x8*)(Br + s * 32 + g * 8);
#pragma unroll
            for (int j = 0; j < 8; j++) {
                int f = s * 32 + g * 8 + j;
                float zz = (float)av[j] + (float)bv[j] + d2v * s_w1c[f] + s_b1[f];
                z[s][j] = fast_silu(zz);
            }
        }
        float sum = 0.f, sq = 0.f;
#pragma unroll
        for (int s = 0; s < 4; s++)
#pragma unroll
            for (int j = 0; j < 8; j++) { sum += z[s][j]; sq += z[s][j] * z[s][j]; }
        sum += __shfl_xor(sum, 16); sq += __shfl_xor(sq, 16);
        sum += __shfl_xor(sum, 32); sq += __shfl_xor(sq, 32);
        float mu = sum * 0.0078125f;
        float var = sq * 0.0078125f - mu * mu;
        float rs = __builtin_amdgcn_rsqf(var + 1e-5f);

        bf16* zp = Z + (size_t)lt * 2048 + g * 128 + r * 8;
#pragma unroll
        for (int s = 0; s < 4; s++) {
            bf16x8 af;
#pragma unroll
            for (int j = 0; j < 8; j++) {
                int f = s * 32 + g * 8 + j;
                af[j] = (bf16)((z[s][j] - mu) * rs * s_g1[f] + s_bt1[f]);
            }
            *(bf16x8*)(zp + s * 512) = af;
        }
    }
}

// ---------------- Phase B: Z -> GEMM1 -> GEMM2 -> scale -> scatter ----------------
// LDS: sW2 34816 + sY 34816 + sSm 1536 = 71168 B -> 2 blocks/CU (4 waves/SIMD).
// W3 B-fragments from global (32KB, L2-resident); unroll 4 caps in-flight loads.
__global__ __launch_bounds__(512, 2) void edgeB_kernel(
    const bf16* __restrict__ Z, const bf16* __restrict__ w2T,
    const bf16* __restrict__ w3T, const float* __restrict__ smalls,
    const float* __restrict__ b4p, const int* __restrict__ e,
    const float* __restrict__ dxv, float* __restrict__ out, int tile0) {
    __shared__ __align__(16) bf16 sW2[128 * 136];
    __shared__ __align__(16) bf16 sY[8 * 16 * 136];
    __shared__ float sSm[3 * 128];

    int tid = threadIdx.x;
    for (int c = tid; c < 2048; c += 512) {
        int row = c >> 4, col = (c & 15) * 8;
        *(bf16x8*)&sW2[row * 136 + col] = *(const bf16x8*)&w2T[row * 128 + col];
    }
    if (tid < 128) {
#pragma unroll
        for (int a = 0; a < 3; a++) sSm[a * 128 + tid] = smalls[(4 + a) * 128 + tid];
    }
    __syncthreads();

    const float* s_b2 = sSm;
    const float* s_b3 = sSm + 128;
    const float* s_W4 = sSm + 256;
    float b4v = b4p[0];

    int lane = tid & 63, wid = tid >> 6;
    int r = lane & 15, g = lane >> 4;
    bf16* yw = &sY[wid * 16 * 136];
    const bf16* w3base = w3T + r * DH + g * 8;
    int wgid = blockIdx.x * 8 + wid;
    int nw = gridDim.x * 8;

    for (int lt = wgid; lt < CT; lt += nw) {
        int base = (tile0 + lt) * 16;
        int ei = e[base + r];

        const bf16* zp = Z + (size_t)lt * 2048 + g * 128 + r * 8;
        bf16x8 af[4];
#pragma unroll
        for (int s = 0; s < 4; s++) af[s] = *(const bf16x8*)(zp + s * 512);

        // GEMM1: y = silu(zn @ W2 + b2) -> per-wave LDS tile (layout exchange)
#pragma unroll
        for (int t = 0; t < 8; t++) {
            f32x4 acc = {0.f, 0.f, 0.f, 0.f};
#pragma unroll
            for (int s = 0; s < 4; s++) {
                bf16x8 wb = *(const bf16x8*)&sW2[(t * 16 + r) * 136 + s * 32 + g * 8];
                acc = __builtin_amdgcn_mfma_f32_16x16x32_bf16(af[s], wb, acc, 0, 0, 0);
            }
            int n = t * 16 + r;
            float b2n = s_b2[n];
#pragma unroll
            for (int jj = 0; jj < 4; jj++)
                yw[(g * 4 + jj) * 136 + n] = (bf16)fast_silu(acc[jj] + b2n);
        }
        bf16x8 a2[4];
#pragma unroll
        for (int s = 0; s < 4; s++)
            a2[s] = *(const bf16x8*)&yw[r * 136 + s * 32 + g * 8];

        // GEMM2 (W3 from global/L2) + fused silu*W4 reduction
        float part[4] = {0.f, 0.f, 0.f, 0.f};
#pragma unroll 4
        for (int t = 0; t < 8; t++) {
            f32x4 acc = {0.f, 0.f, 0.f, 0.f};
#pragma unroll
            for (int s = 0; s < 4; s++) {
                bf16x8 wb = *(const bf16x8*)(w3base + t * 16 * DH + s * 32);
                acc = __builtin_amdgcn_mfma_f32_16x16x32_bf16(a2[s], wb, acc, 0, 0, 0);
            }
            int n = t * 16 + r;
            float b3n = s_b3[n], w4n = s_W4[n];
#pragma unroll
            for (int jj = 0; jj < 4; jj++)
                part[jj] += fast_silu(acc[jj] + b3n) * w4n;
        }
#pragma unroll
        for (int jj = 0; jj < 4; jj++) {
            part[jj] += __shfl_xor(part[jj], 1);
            part[jj] += __shfl_xor(part[jj], 2);
            part[jj] += __shfl_xor(part[jj], 4);
            part[jj] += __shfl_xor(part[jj], 8);
        }
        // scatter: lane = m*4 + c  (edge m = lane>>2, component c = lane&3)
        {
            int m = lane >> 2, c3 = lane & 3;
            int jj = m & 3;
            float sc = (jj == 0) ? part[0] : (jj == 1) ? part[1]
                     : (jj == 2) ? part[2] : part[3];
            float scale = sc + b4v;
            int eim = __shfl(ei, m);
            if (c3 < 3)
                atomicAdd(&out[(size_t)eim * 3 + c3],
                          dxv[(size_t)(base + m) * 3 + c3] * scale);
        }
    }
}

extern "C" void kernel_launch(void* const* d_in, const int* in_sizes, int n_in,
                              void* d_out, int out_size, void* d_ws, size_t ws_size,
                              hipStream_t stream) {
    const float* h   = (const float*)d_in[0];
    const float* x   = (const float*)d_in[1];
    const int*   e   = (const int*)d_in[2];
    const float* dxv = (const float*)d_in[3];
    const float* d2  = (const float*)d_in[4];
    const float* W1  = (const float*)d_in[5];
    const float* b1  = (const float*)d_in[6];
    const float* g1  = (const float*)d_in[7];
    const float* bt1 = (const float*)d_in[8];
    const float* W2  = (const float*)d_in[9];
    const float* b2  = (const float*)d_in[10];
    const float* W3  = (const float*)d_in[11];
    const float* b3  = (const float*)d_in[12];
    const float* W4  = (const float*)d_in[13];
    const float* b4  = (const float*)d_in[14];

    char* ws = (char*)d_ws;
    bf16* An     = (bf16*)(ws);                        // 12,800,000
    bf16* Bn     = (bf16*)(ws + 12800000);             // 12,800,000
    bf16* w1aT   = (bf16*)(ws + 25600000);             // 32768
    bf16* w1bT   = (bf16*)(ws + 25632768);             // 32768
    bf16* w2T    = (bf16*)(ws + 25665536);             // 32768
    bf16* w3T    = (bf16*)(ws + 25698304);             // 32768
    float* smalls = (float*)(ws + 25731072);           // 3584
    bf16* Z      = (bf16*)(ws + 25734656);             // 51,200,000 (12500 tiles * 4KB)
    float* out   = (float*)d_out;

    prep_kernel<<<64, 256, 0, stream>>>(W1, W2, W3, b1, g1, bt1, b2, b3, W4,
                                        w1aT, w1bT, w2T, w3T, smalls);
    node_kernel<<<(NN / 16 + 3) / 4, 256, 0, stream>>>(h, w1aT, w1bT, An, Bn);
    init_kernel<<<(NN * 3 + 255) / 256, 256, 0, stream>>>(x, out, NN * 3);

    for (int c = 0; c < NCHUNK; ++c) {
        int tile0 = c * CT;
        edgeA_kernel<<<1024, 256, 0, stream>>>(An, Bn, smalls, e, d2, Z, tile0);
        edgeB_kernel<<<512, 512, 0, stream>>>(Z, w2T, w3T, smalls, b4,
                                              e, dxv, out, tile0);
    }
}